// Round 5
// baseline (67.235 us; speedup 1.0000x reference)
//
#include <hip/hip_runtime.h>
#include <hip/hip_bf16.h>

// x[4096,2048] f32, w[2048,2048] f32, bias[2048] f32, indices = permutation of
// K axis applied to BOTH operands -> cancels out of the einsum; unused.
#define M_DIM 4096
#define N_DIM 2048
#define K_DIM 2048

// 256x128 tile, BK=64, 4 waves (2M x 2N), 128x64 per wave (m201 wave shape).
// Grid = 16 x 16 = 256 blocks = 1 block/CU. 1 wave/SIMD, full VGPR budget.
#define BM 256
#define BN 128
#define BK 64
#define NT (K_DIM / BK)      // 32 K-tiles
#define A_TILE (BM * BK)     // 16384 elems = 32 KiB
#define B_TILE (BN * BK)     // 8192 elems  = 16 KiB

typedef __bf16 bf16x8 __attribute__((ext_vector_type(8)));
typedef float f32x4 __attribute__((ext_vector_type(4)));
typedef unsigned short u16x8 __attribute__((ext_vector_type(8)));

__device__ __forceinline__ unsigned short f32_to_bf16_rne(float f) {
  unsigned int u = __float_as_uint(f);
  u += 0x7fffu + ((u >> 16) & 1u);
  return (unsigned short)(u >> 16);
}

// ---- merged f32 -> bf16 conversion for x and w ----
__global__ __launch_bounds__(256) void cvt_both(
    const float* __restrict__ x, const float* __restrict__ w,
    unsigned short* __restrict__ out, int xn8, int totn8) {
  int i = blockIdx.x * 256 + threadIdx.x;
  if (i >= totn8) return;
  const float* src = (i < xn8) ? (x + (size_t)i * 8)
                               : (w + (size_t)(i - xn8) * 8);
  f32x4 a = reinterpret_cast<const f32x4*>(src)[0];
  f32x4 b = reinterpret_cast<const f32x4*>(src)[1];
  u16x8 o;
  o[0] = f32_to_bf16_rne(a[0]); o[1] = f32_to_bf16_rne(a[1]);
  o[2] = f32_to_bf16_rne(a[2]); o[3] = f32_to_bf16_rne(a[3]);
  o[4] = f32_to_bf16_rne(b[0]); o[5] = f32_to_bf16_rne(b[1]);
  o[6] = f32_to_bf16_rne(b[2]); o[7] = f32_to_bf16_rne(b[3]);
  reinterpret_cast<u16x8*>(out)[i] = o;
}

__device__ __forceinline__ void gload_lds16(const unsigned short* g, unsigned short* l) {
  __builtin_amdgcn_global_load_lds(
      (const __attribute__((address_space(1))) unsigned int*)g,
      (__attribute__((address_space(3))) unsigned int*)l, 16, 0, 0);
}

#define LD8(p) (*reinterpret_cast<const bf16x8*>(p))
#define VMWAIT_(n) asm volatile("s_waitcnt vmcnt(" #n ")" ::: "memory")
#define VMWAIT(n) VMWAIT_(n)
#define SBAR() __builtin_amdgcn_s_barrier()
#define SCHED() __builtin_amdgcn_sched_barrier(0)

// Derived-waits pipelined bf16 GEMM, 128x64 per-wave tile.
// C[M][N] = A[M][K] * B[N][K]^T + bias.
// Per wave per K-tile: 24 ds_read_b128, 64 MFMA (vs 16/32 at 64x64) --
// LDS-read bytes/FLOP down 25%, putting the LDS pipe at ~parity with the
// MFMA pipe CU-wide. Reads one phase ahead (counted lgkmcnt, pre-satisfied);
// triple LDS buffer, stage distance 2, vmcnt(12) once per tile (never drain
// in main loop). Swizzle as R2 (measured 0 bank conflicts).
__global__ __launch_bounds__(256, 1) void gemm_4w(
    const unsigned short* __restrict__ A,   // [M][K] bf16 bits
    const unsigned short* __restrict__ B,   // [N][K] bf16 bits
    const float* __restrict__ bias,         // [N]
    float* __restrict__ C) {                // [M][N] f32
  __shared__ unsigned short As[3 * A_TILE]; // 96 KiB
  __shared__ unsigned short Bs[3 * B_TILE]; // 48 KiB

  const int tid  = threadIdx.x;
  const int lane = tid & 63;
  const int wave = tid >> 6;   // 0..3
  const int wr   = wave >> 1;  // 0..1 (M: 128-row half)
  const int wc   = wave & 1;   // 0..1 (N: 64-col half)
  const int bn   = blockIdx.x; // 0..15
  const int bm   = blockIdx.y; // 0..15

  // ---- staging: 256 thr x 16B = 32 rows x 128B per gload issue ----
  // A: 8 chunks of 32 rows; B: 4 chunks. 12 gloads/thread per K-tile.
  const int srow   = tid >> 3;                 // 0..31
  const int schunk = (tid & 7) ^ (srow & 7);   // pre-swizzled global source
  const unsigned short* Ag[8];
  const unsigned short* Bg[4];
#pragma unroll
  for (int j = 0; j < 8; ++j)
    Ag[j] = A + (size_t)(bm * BM + j * 32 + srow) * K_DIM + schunk * 8;
#pragma unroll
  for (int j = 0; j < 4; ++j)
    Bg[j] = B + (size_t)(bn * BN + j * 32 + srow) * K_DIM + schunk * 8;

#define STAGE_ALL(buf, k0) do { \
    unsigned short* _da = &As[(buf) * A_TILE + tid * 8]; \
    unsigned short* _db = &Bs[(buf) * B_TILE + tid * 8]; \
    gload_lds16(Ag[0] + (k0), _da); \
    gload_lds16(Ag[1] + (k0), _da + 2048); \
    gload_lds16(Ag[2] + (k0), _da + 4096); \
    gload_lds16(Ag[3] + (k0), _da + 6144); \
    gload_lds16(Ag[4] + (k0), _da + 8192); \
    gload_lds16(Ag[5] + (k0), _da + 10240); \
    gload_lds16(Ag[6] + (k0), _da + 12288); \
    gload_lds16(Ag[7] + (k0), _da + 14336); \
    gload_lds16(Bg[0] + (k0), _db); \
    gload_lds16(Bg[1] + (k0), _db + 2048); \
    gload_lds16(Bg[2] + (k0), _db + 4096); \
    gload_lds16(Bg[3] + (k0), _db + 6144); \
  } while (0)

  // ---- ds_read offsets (elements): row-major [rows][64] per buffer,
  // element (m,k): addr = m*64 + ((k>>3) ^ (m&7))*8 + (k&7).
  // Fragment: row (..+fr), k = kk*32 + qq*8.
  const int fr = lane & 15;
  const int qq = lane >> 4;
  const int xr = fr & 7;
  int aoff[8][2], boff[4][2];
#pragma unroll
  for (int mi = 0; mi < 8; ++mi)
#pragma unroll
    for (int kk = 0; kk < 2; ++kk)
      aoff[mi][kk] = ((wr * 128 + mi * 16 + fr) * 8 + ((kk * 4 + qq) ^ xr)) * 8;
#pragma unroll
  for (int ni = 0; ni < 4; ++ni)
#pragma unroll
    for (int kk = 0; kk < 2; ++kk)
      boff[ni][kk] = ((wc * 64 + ni * 16 + fr) * 8 + ((kk * 4 + qq) ^ xr)) * 8;

  const f32x4 z = {0.f, 0.f, 0.f, 0.f};
  f32x4 acc[8][4];
#pragma unroll
  for (int i = 0; i < 8; ++i)
#pragma unroll
    for (int j = 0; j < 4; ++j) acc[i][j] = z;

  // Double register subtile sets (phase-ahead pipeline).
  bf16x8 avA[8], bvA[4], avB[8], bvB[4];

#define READ_SET(av, bv, bufi, kk) do { \
    const unsigned short* Asb = &As[(bufi) * A_TILE]; \
    const unsigned short* Bsb = &Bs[(bufi) * B_TILE]; \
    bv[0] = LD8(Bsb + boff[0][kk]); bv[1] = LD8(Bsb + boff[1][kk]); \
    bv[2] = LD8(Bsb + boff[2][kk]); bv[3] = LD8(Bsb + boff[3][kk]); \
    av[0] = LD8(Asb + aoff[0][kk]); av[1] = LD8(Asb + aoff[1][kk]); \
    av[2] = LD8(Asb + aoff[2][kk]); av[3] = LD8(Asb + aoff[3][kk]); \
    av[4] = LD8(Asb + aoff[4][kk]); av[5] = LD8(Asb + aoff[5][kk]); \
    av[6] = LD8(Asb + aoff[6][kk]); av[7] = LD8(Asb + aoff[7][kk]); \
  } while (0)

#define MFMA_ALL(av, bv) do { \
    __builtin_amdgcn_s_setprio(1); \
    _Pragma("unroll") \
    for (int mi = 0; mi < 8; ++mi) { \
      acc[mi][0] = __builtin_amdgcn_mfma_f32_16x16x32_bf16(av[mi], bv[0], acc[mi][0], 0, 0, 0); \
      acc[mi][1] = __builtin_amdgcn_mfma_f32_16x16x32_bf16(av[mi], bv[1], acc[mi][1], 0, 0, 0); \
      acc[mi][2] = __builtin_amdgcn_mfma_f32_16x16x32_bf16(av[mi], bv[2], acc[mi][2], 0, 0, 0); \
      acc[mi][3] = __builtin_amdgcn_mfma_f32_16x16x32_bf16(av[mi], bv[3], acc[mi][3], 0, 0, 0); \
    } \
    __builtin_amdgcn_s_setprio(0); \
  } while (0)

  // Tile t (buf = t%3, literals via unroll-by-3):
  // Phase A: stage(t+2) [12 gloads]; read B-regs(t) from buf[t]; MFMA A-regs(t);
  //          vmcnt(12) [stage(t+1) landed, stage(t+2) in flight]; barrier.
  // Phase B: read A-regs(t+1) from buf[t+1]; MFMA B-regs(t); barrier.
#define TILE_MAIN(bufi, stgbufi, stgt) do { \
    STAGE_ALL(stgbufi, (stgt) * BK); \
    READ_SET(avB, bvB, bufi, 1); \
    SCHED(); \
    MFMA_ALL(avA, bvA); \
    SCHED(); \
    VMWAIT(12); \
    SBAR(); \
    SCHED(); \
    READ_SET(avA, bvA, ((bufi) + 1) % 3, 0); \
    SCHED(); \
    MFMA_ALL(avB, bvB); \
    SBAR(); \
    SCHED(); \
  } while (0)

  // prologue: stage tiles 0,1; wait tile 0 (leave tile 1's 12 in flight).
  STAGE_ALL(0, 0);
  STAGE_ALL(1, BK);
  VMWAIT(12);
  SBAR();
  SCHED();
  READ_SET(avA, bvA, 0, 0);
  SCHED();

  // main loop: tiles 0..29 (staging tiles 2..31), unrolled by 3.
#pragma unroll 1
  for (int s = 0; s < 10; ++s) {
    const int t0 = s * 3;
    TILE_MAIN(0, 2, t0 + 2);
    TILE_MAIN(1, 0, t0 + 3);
    TILE_MAIN(2, 1, t0 + 4);
  }

  // ---- tail: tiles 30 (buf0) and 31 (buf1), no staging ----
  READ_SET(avB, bvB, 0, 1);
  SCHED();
  MFMA_ALL(avA, bvA);
  SCHED();
  VMWAIT(0);
  SBAR();
  SCHED();
  READ_SET(avA, bvA, 1, 0);
  SCHED();
  MFMA_ALL(avB, bvB);
  READ_SET(avB, bvB, 1, 1);
  SCHED();
  MFMA_ALL(avA, bvA);
  MFMA_ALL(avB, bvB);

  // ---- epilogue: C/D layout col = lane&15, row = (lane>>4)*4 + r ----
  const int orow0 = bm * BM + wr * 128 + qq * 4;
  const int ocol0 = bn * BN + wc * 64 + fr;
#pragma unroll
  for (int ni = 0; ni < 4; ++ni) {
    const int col = ocol0 + ni * 16;
    const float bv = bias[col];
#pragma unroll
    for (int mi = 0; mi < 8; ++mi) {
      const int row = orow0 + mi * 16;
#pragma unroll
      for (int r = 0; r < 4; ++r)
        C[(size_t)(row + r) * N_DIM + col] = acc[mi][ni][r] + bv;
    }
  }
#undef TILE_MAIN
#undef MFMA_ALL
#undef READ_SET
#undef STAGE_ALL
}

// ---- safety fallback ----
__global__ __launch_bounds__(256) void gemm_f32_naive(
    const float* __restrict__ X, const float* __restrict__ W,
    const float* __restrict__ bias, float* __restrict__ C) {
  int o = blockIdx.x * 256 + threadIdx.x;
  if (o >= M_DIM * N_DIM) return;
  int m = o / N_DIM, n = o % N_DIM;
  const float* xr = X + (size_t)m * K_DIM;
  const float* wr = W + (size_t)n * K_DIM;
  float s = 0.f;
  for (int k = 0; k < K_DIM; ++k) s += xr[k] * wr[k];
  C[o] = s + bias[n];
}

extern "C" void kernel_launch(void* const* d_in, const int* in_sizes, int n_in,
                              void* d_out, int out_size, void* d_ws, size_t ws_size,
                              hipStream_t stream) {
  const float* x    = (const float*)d_in[0];
  const float* w    = (const float*)d_in[1];
  const float* bias = (const float*)d_in[2];
  float* out = (float*)d_out;

  const size_t x_elems = (size_t)M_DIM * K_DIM;
  const size_t w_elems = (size_t)N_DIM * K_DIM;
  const size_t need = (x_elems + w_elems) * sizeof(unsigned short);

  if (ws_size < need) {
    gemm_f32_naive<<<(M_DIM * N_DIM + 255) / 256, 256, 0, stream>>>(x, w, bias, out);
    return;
  }

  unsigned short* xb = (unsigned short*)d_ws;
  unsigned short* wb = xb + x_elems;

  const int xn8 = (int)(x_elems / 8);
  const int totn8 = (int)((x_elems + w_elems) / 8);
  cvt_both<<<(totn8 + 255) / 256, 256, 0, stream>>>(x, w, xb, xn8, totn8);

  dim3 grid(N_DIM / BN, M_DIM / BM);  // (16, 16) = 256 blocks, 1/CU
  gemm_4w<<<grid, 256, 0, stream>>>(xb, wb, bias, out);
}

// Round 6
// 53.335 us; speedup vs baseline: 1.2606x; 1.2606x over previous
//
#include <hip/hip_runtime.h>
#include <hip/hip_bf16.h>

// x[4096,2048] f32, w[2048,2048] f32, bias[2048] f32, indices = permutation of
// K axis applied to BOTH operands -> cancels out of the einsum; unused.
#define M_DIM 4096
#define N_DIM 2048
#define K_DIM 2048

// 128x128 tile, BK=64, 4 waves (2M x 2N), 64x64 per wave.
// Grid = 16 x 32 = 512 blocks = 2 blocks/CU (the TLP lever: async blocks
// cover each other's vmcnt/barrier stalls -- m114 mechanism).
// LDS = 2 x (16K A + 16K B) = 64 KiB -> two blocks co-resident.
#define BM 128
#define BN 128
#define BK 64
#define NT (K_DIM / BK)      // 32 K-tiles
#define A_TILE (BM * BK)     // 8192 elems = 16 KiB
#define B_TILE (BN * BK)     // 8192 elems = 16 KiB

typedef __bf16 bf16x8 __attribute__((ext_vector_type(8)));
typedef float f32x4 __attribute__((ext_vector_type(4)));
typedef unsigned short u16x8 __attribute__((ext_vector_type(8)));

__device__ __forceinline__ unsigned short f32_to_bf16_rne(float f) {
  unsigned int u = __float_as_uint(f);
  u += 0x7fffu + ((u >> 16) & 1u);
  return (unsigned short)(u >> 16);
}

// ---- merged f32 -> bf16 conversion for x and w ----
__global__ __launch_bounds__(256) void cvt_both(
    const float* __restrict__ x, const float* __restrict__ w,
    unsigned short* __restrict__ out, int xn8, int totn8) {
  int i = blockIdx.x * 256 + threadIdx.x;
  if (i >= totn8) return;
  const float* src = (i < xn8) ? (x + (size_t)i * 8)
                               : (w + (size_t)(i - xn8) * 8);
  f32x4 a = reinterpret_cast<const f32x4*>(src)[0];
  f32x4 b = reinterpret_cast<const f32x4*>(src)[1];
  u16x8 o;
  o[0] = f32_to_bf16_rne(a[0]); o[1] = f32_to_bf16_rne(a[1]);
  o[2] = f32_to_bf16_rne(a[2]); o[3] = f32_to_bf16_rne(a[3]);
  o[4] = f32_to_bf16_rne(b[0]); o[5] = f32_to_bf16_rne(b[1]);
  o[6] = f32_to_bf16_rne(b[2]); o[7] = f32_to_bf16_rne(b[3]);
  reinterpret_cast<u16x8*>(out)[i] = o;
}

__device__ __forceinline__ void gload_lds16(const unsigned short* g, unsigned short* l) {
  __builtin_amdgcn_global_load_lds(
      (const __attribute__((address_space(1))) unsigned int*)g,
      (__attribute__((address_space(3))) unsigned int*)l, 16, 0, 0);
}

#define LD8(p) (*reinterpret_cast<const bf16x8*>(p))
#define VMWAIT_(n) asm volatile("s_waitcnt vmcnt(" #n ")" ::: "memory")
#define VMWAIT(n) VMWAIT_(n)
#define SBAR() __builtin_amdgcn_s_barrier()
#define SCHED() __builtin_amdgcn_sched_barrier(0)

// 2-blocks/CU double-buffered bf16 GEMM. C[M][N] = A[M][K]*B[N][K]^T + bias.
// Per K-tile: stage(t+1) -> other buffer; read kk=1 regs; MFMA kk=0 (regs
// read last tile); MFMA kk=1 (forces lgkm drain of this tile's reads BEFORE
// the barrier -- no ds_read in flight across it); vmcnt(0); barrier; read
// kk=0 regs for t+1 from the freshly staged buffer. One barrier per tile.
// The per-tile vmcnt(0) drain is covered by the co-resident block's compute.
// Swizzle as R2 (measured 0 bank conflicts).
__global__ __launch_bounds__(256, 2) void gemm_db(
    const unsigned short* __restrict__ A,   // [M][K] bf16 bits
    const unsigned short* __restrict__ B,   // [N][K] bf16 bits
    const float* __restrict__ bias,         // [N]
    float* __restrict__ C) {                // [M][N] f32
  __shared__ unsigned short As[2 * A_TILE]; // 32 KiB
  __shared__ unsigned short Bs[2 * B_TILE]; // 32 KiB

  const int tid  = threadIdx.x;
  const int lane = tid & 63;
  const int wave = tid >> 6;   // 0..3
  const int wr   = wave >> 1;  // 0..1 (M)
  const int wc   = wave & 1;   // 0..1 (N)
  const int bn   = blockIdx.x; // 0..15
  const int bm   = blockIdx.y; // 0..31

  // ---- staging: 256 thr x 16B = 32 rows x 128B per gload issue ----
  // A: 4 issues of 32 rows; B: 4 issues. 8 gloads/thread per K-tile.
  const int srow   = tid >> 3;                 // 0..31
  const int schunk = (tid & 7) ^ (srow & 7);   // pre-swizzled global source
  const unsigned short* Ag[4];
  const unsigned short* Bg[4];
#pragma unroll
  for (int j = 0; j < 4; ++j) {
    Ag[j] = A + (size_t)(bm * BM + j * 32 + srow) * K_DIM + schunk * 8;
    Bg[j] = B + (size_t)(bn * BN + j * 32 + srow) * K_DIM + schunk * 8;
  }

#define STAGE_ALL(buf, k0) do { \
    unsigned short* _da = &As[(buf) * A_TILE + tid * 8]; \
    unsigned short* _db = &Bs[(buf) * B_TILE + tid * 8]; \
    gload_lds16(Ag[0] + (k0), _da); \
    gload_lds16(Ag[1] + (k0), _da + 2048); \
    gload_lds16(Ag[2] + (k0), _da + 4096); \
    gload_lds16(Ag[3] + (k0), _da + 6144); \
    gload_lds16(Bg[0] + (k0), _db); \
    gload_lds16(Bg[1] + (k0), _db + 2048); \
    gload_lds16(Bg[2] + (k0), _db + 4096); \
    gload_lds16(Bg[3] + (k0), _db + 6144); \
  } while (0)

  // ---- ds_read offsets (elements): row-major [128][64] per buffer,
  // element (r,k): addr = r*64 + ((k>>3) ^ (r&7))*8 + (k&7).
  const int fr = lane & 15;
  const int qq = lane >> 4;
  const int xr = fr & 7;
  int aoff[4][2], boff[4][2];
#pragma unroll
  for (int mi = 0; mi < 4; ++mi)
#pragma unroll
    for (int kk = 0; kk < 2; ++kk)
      aoff[mi][kk] = ((wr * 64 + mi * 16 + fr) * 8 + ((kk * 4 + qq) ^ xr)) * 8;
#pragma unroll
  for (int ni = 0; ni < 4; ++ni)
#pragma unroll
    for (int kk = 0; kk < 2; ++kk)
      boff[ni][kk] = ((wc * 64 + ni * 16 + fr) * 8 + ((kk * 4 + qq) ^ xr)) * 8;

  const f32x4 z = {0.f, 0.f, 0.f, 0.f};
  f32x4 acc[4][4];
#pragma unroll
  for (int i = 0; i < 4; ++i)
#pragma unroll
    for (int j = 0; j < 4; ++j) acc[i][j] = z;

  // Double register subtile sets (phase-ahead pipeline).
  bf16x8 avA[4], bvA[4], avB[4], bvB[4];

#define READ_SET(av, bv, bufi, kk) do { \
    const unsigned short* Asb = &As[(bufi) * A_TILE]; \
    const unsigned short* Bsb = &Bs[(bufi) * B_TILE]; \
    bv[0] = LD8(Bsb + boff[0][kk]); bv[1] = LD8(Bsb + boff[1][kk]); \
    bv[2] = LD8(Bsb + boff[2][kk]); bv[3] = LD8(Bsb + boff[3][kk]); \
    av[0] = LD8(Asb + aoff[0][kk]); av[1] = LD8(Asb + aoff[1][kk]); \
    av[2] = LD8(Asb + aoff[2][kk]); av[3] = LD8(Asb + aoff[3][kk]); \
  } while (0)

#define MFMA_ALL(av, bv) do { \
    __builtin_amdgcn_s_setprio(1); \
    _Pragma("unroll") \
    for (int mi = 0; mi < 4; ++mi) { \
      acc[mi][0] = __builtin_amdgcn_mfma_f32_16x16x32_bf16(av[mi], bv[0], acc[mi][0], 0, 0, 0); \
      acc[mi][1] = __builtin_amdgcn_mfma_f32_16x16x32_bf16(av[mi], bv[1], acc[mi][1], 0, 0, 0); \
      acc[mi][2] = __builtin_amdgcn_mfma_f32_16x16x32_bf16(av[mi], bv[2], acc[mi][2], 0, 0, 0); \
      acc[mi][3] = __builtin_amdgcn_mfma_f32_16x16x32_bf16(av[mi], bv[3], acc[mi][3], 0, 0, 0); \
    } \
    __builtin_amdgcn_s_setprio(0); \
  } while (0)

  // Tile t (p = t&1, literal): avA/bvA hold kk=0 regs (read last tile).
#define TILE(p_, t_) do { \
    STAGE_ALL((p_) ^ 1, ((t_) + 1) * BK); \
    READ_SET(avB, bvB, p_, 1); \
    SCHED(); \
    MFMA_ALL(avA, bvA); \
    MFMA_ALL(avB, bvB); \
    SCHED(); \
    VMWAIT(0); \
    SBAR(); \
    SCHED(); \
    READ_SET(avA, bvA, (p_) ^ 1, 0); \
  } while (0)

  // prologue: stage tile 0, wait, pre-read kk=0 regs.
  STAGE_ALL(0, 0);
  VMWAIT(0);
  SBAR();
  SCHED();
  READ_SET(avA, bvA, 0, 0);

  // main loop: tiles 0..29 (each stages t+1), unrolled by 2.
#pragma unroll 1
  for (int s = 0; s < 15; ++s) {
    TILE(0, 2 * s);
    TILE(1, 2 * s + 1);
  }
  TILE(0, 30);  // stages tile 31 -> buf1; trailing READ_SET pulls kk=0 of t31

  // tail: tile 31 (buf1), no staging, no barrier needed.
  READ_SET(avB, bvB, 1, 1);
  SCHED();
  MFMA_ALL(avA, bvA);
  MFMA_ALL(avB, bvB);

  // ---- epilogue: C/D layout col = lane&15, row = (lane>>4)*4 + r ----
  const int orow0 = bm * BM + wr * 64 + qq * 4;
  const int ocol0 = bn * BN + wc * 64 + fr;
#pragma unroll
  for (int ni = 0; ni < 4; ++ni) {
    const int col = ocol0 + ni * 16;
    const float bv = bias[col];
#pragma unroll
    for (int mi = 0; mi < 4; ++mi) {
      const int row = orow0 + mi * 16;
#pragma unroll
      for (int r = 0; r < 4; ++r)
        C[(size_t)(row + r) * N_DIM + col] = acc[mi][ni][r] + bv;
    }
  }
#undef TILE
#undef MFMA_ALL
#undef READ_SET
#undef STAGE_ALL
}

// ---- safety fallback ----
__global__ __launch_bounds__(256) void gemm_f32_naive(
    const float* __restrict__ X, const float* __restrict__ W,
    const float* __restrict__ bias, float* __restrict__ C) {
  int o = blockIdx.x * 256 + threadIdx.x;
  if (o >= M_DIM * N_DIM) return;
  int m = o / N_DIM, n = o % N_DIM;
  const float* xr = X + (size_t)m * K_DIM;
  const float* wr = W + (size_t)n * K_DIM;
  float s = 0.f;
  for (int k = 0; k < K_DIM; ++k) s += xr[k] * wr[k];
  C[o] = s + bias[n];
}

extern "C" void kernel_launch(void* const* d_in, const int* in_sizes, int n_in,
                              void* d_out, int out_size, void* d_ws, size_t ws_size,
                              hipStream_t stream) {
  const float* x    = (const float*)d_in[0];
  const float* w    = (const float*)d_in[1];
  const float* bias = (const float*)d_in[2];
  float* out = (float*)d_out;

  const size_t x_elems = (size_t)M_DIM * K_DIM;
  const size_t w_elems = (size_t)N_DIM * K_DIM;
  const size_t need = (x_elems + w_elems) * sizeof(unsigned short);

  if (ws_size < need) {
    gemm_f32_naive<<<(M_DIM * N_DIM + 255) / 256, 256, 0, stream>>>(x, w, bias, out);
    return;
  }

  unsigned short* xb = (unsigned short*)d_ws;
  unsigned short* wb = xb + x_elems;

  const int xn8 = (int)(x_elems / 8);
  const int totn8 = (int)((x_elems + w_elems) / 8);
  cvt_both<<<(totn8 + 255) / 256, 256, 0, stream>>>(x, w, xb, xn8, totn8);

  dim3 grid(N_DIM / BN, M_DIM / BM);  // (16, 32) = 512 blocks = 2/CU
  gemm_db<<<grid, 256, 0, stream>>>(xb, wb, bias, out);
}